// Round 3
// baseline (154.465 us; speedup 1.0000x reference)
//
#include <hip/hip_runtime.h>
#include <hip/hip_bf16.h>

typedef _Float16 f16x8 __attribute__((ext_vector_type(8)));
typedef float f32x4 __attribute__((ext_vector_type(4)));

#define BM 128
#define BKH 96      // K-halves per chunk (8 features x 12 slots)
#define LDA 104     // padded LDS row stride (halves): 208B = 13*16B
#define NCHUNK 32   // 3072 / 96
#define IN_F 256
#define OUT_F 256
#define KDIM 3072   // 256 * 12

// Build W2[o][k] fp16, k = i*12 + m ; m<11 -> coeff[o][i][m], m==11 -> base_w[o][i]
__global__ __launch_bounds__(256) void prep_w(const float* __restrict__ coeff,
                                              const float* __restrict__ base_w,
                                              _Float16* __restrict__ W2) {
  const int o = blockIdx.x;
  for (int k2 = threadIdx.x; k2 < KDIM / 2; k2 += 256) {
    const int k = k2 * 2;
    float v0, v1;
    {
      const int i = k / 12, m = k % 12;
      v0 = (m == 11) ? base_w[o * IN_F + i] : coeff[(o * IN_F + i) * 11 + m];
    }
    {
      const int k1 = k + 1;
      const int i = k1 / 12, m = k1 % 12;
      v1 = (m == 11) ? base_w[o * IN_F + i] : coeff[(o * IN_F + i) * 11 + m];
    }
    union { _Float16 h[2]; unsigned int u; } p;
    p.h[0] = (_Float16)v0;
    p.h[1] = (_Float16)v1;
    *(unsigned int*)&W2[(size_t)o * KDIM + k] = p.u;
  }
}

__global__ __launch_bounds__(512) void kan_fused(const float* __restrict__ x,
                                                 const float* __restrict__ gamma,
                                                 const float* __restrict__ beta,
                                                 const _Float16* __restrict__ W2,
                                                 float* __restrict__ out) {
  __shared__ _Float16 A_lds[BM * LDA];
  __shared__ float mu_s[BM], rs_s[BM];
  __shared__ float g_s[IN_F], b_s[IN_F];

  const int tid  = threadIdx.x;
  const int lane = tid & 63;
  const int wid  = tid >> 6;
  const int row0 = blockIdx.x * BM;

  // gamma/beta to LDS
  if (tid < IN_F) g_s[tid] = gamma[tid];
  else            b_s[tid - IN_F] = beta[tid - IN_F];

  // ---- LayerNorm stats: one wave per row ----
  for (int rr = wid; rr < BM; rr += 8) {
    const float4 v = *(const float4*)(x + (size_t)(row0 + rr) * IN_F + lane * 4);
    float s  = v.x + v.y + v.z + v.w;
    float sq = v.x * v.x + v.y * v.y + v.z * v.z + v.w * v.w;
    #pragma unroll
    for (int off = 32; off >= 1; off >>= 1) {
      s  += __shfl_xor(s, off);
      sq += __shfl_xor(sq, off);
    }
    if (lane == 0) {
      const float mu  = s * (1.0f / 256.0f);
      const float var = sq * (1.0f / 256.0f) - mu * mu;
      mu_s[rr] = mu;
      rs_s[rr] = 1.0f / sqrtf(var + 1e-5f);
    }
  }
  __syncthreads();

  // wave tile: 2 x 4 waves, each 64x64 output
  const int wr   = wid >> 2;          // 0..1
  const int wc   = wid & 3;           // 0..3
  const int lrow = lane & 15;
  const int lk8  = (lane >> 4) * 8;

  f32x4 acc[4][4] = {};

  // production mapping: 1024 (row, feature) pairs per chunk, 2 per thread
  const int pr  = tid & 127;
  const int piq = tid >> 7;           // 0..3

  const _Float16* wbase = W2 + (size_t)(wc * 64 + lrow) * KDIM + lk8;

  for (int c = 0; c < NCHUNK; ++c) {
    const int i0 = c * 8;
    __syncthreads();                  // previous chunk's MFMA reads done
    // ---- produce A tile: rows of [11 basis | silu] fp16 ----
    {
      const int i = i0 + piq * 2;
      const float2 xv = *(const float2*)(x + (size_t)(row0 + pr) * IN_F + i);
      const float mu = mu_s[pr], rs = rs_s[pr];
      _Float16 h[24];
      #pragma unroll
      for (int q = 0; q < 2; ++q) {
        const float xr = (q == 0) ? xv.x : xv.y;
        const float n  = (xr - mu) * rs * g_s[i + q] + b_s[i + q];
        const float v  = (n + 1.75f) * 4.0f;    // knots t_j = -1.75 + 0.25*j
        const float fj = floorf(v);
        const int j = (v >= 0.0f && v < 14.0f) ? (int)fj : 999; // out of grid -> all-zero basis
        const float u  = v - fj;
        const float u2 = u * u, u3 = u2 * u;
        const float w0 = (1.0f / 6.0f) * (1.0f - 3.0f * u + 3.0f * u2 - u3);
        const float w1 = (1.0f / 6.0f) * (3.0f * u3 - 6.0f * u2 + 4.0f);
        const float w2 = (1.0f / 6.0f) * (-3.0f * u3 + 3.0f * u2 + 3.0f * u + 1.0f);
        const float w3 = (1.0f / 6.0f) * u3;
        #pragma unroll
        for (int m = 0; m < 11; ++m) {          // tap index t = m - (j-3)
          const int t = m - j + 3;
          float w = 0.0f;
          w = (t == 0) ? w0 : w;
          w = (t == 1) ? w1 : w;
          w = (t == 2) ? w2 : w;
          w = (t == 3) ? w3 : w;
          h[q * 12 + m] = (_Float16)w;
        }
        h[q * 12 + 11] = (_Float16)(xr / (1.0f + __expf(-xr)));  // silu(raw x)
      }
      char* db = (char*)&A_lds[pr * LDA] + piq * 48;
      *(f16x8*)(db)      = *(const f16x8*)&h[0];
      *(f16x8*)(db + 16) = *(const f16x8*)&h[8];
      *(f16x8*)(db + 32) = *(const f16x8*)&h[16];
    }
    __syncthreads();                  // A tile ready
    // ---- MFMA: A from LDS, B straight from L2 ----
    const _Float16* wk = wbase + c * BKH;
    #pragma unroll
    for (int fk = 0; fk < 3; ++fk) {
      f16x8 a[4], b[4];
      #pragma unroll
      for (int fm = 0; fm < 4; ++fm)
        a[fm] = *(const f16x8*)&A_lds[(wr * 64 + fm * 16 + lrow) * LDA + fk * 32 + lk8];
      #pragma unroll
      for (int fn = 0; fn < 4; ++fn)
        b[fn] = *(const f16x8*)(wk + (size_t)fn * 16 * KDIM + fk * 32);
      #pragma unroll
      for (int fm = 0; fm < 4; ++fm)
        #pragma unroll
        for (int fn = 0; fn < 4; ++fn)
          acc[fm][fn] = __builtin_amdgcn_mfma_f32_16x16x32_f16(a[fm], b[fn], acc[fm][fn], 0, 0, 0);
    }
  }

  // ---- epilogue: D lane layout col = lane&15, row = (lane>>4)*4 + r ----
  const int orow0 = row0 + wr * 64 + (lane >> 4) * 4;
  const int ocol0 = wc * 64 + lrow;
  #pragma unroll
  for (int fm = 0; fm < 4; ++fm)
    #pragma unroll
    for (int fn = 0; fn < 4; ++fn)
      #pragma unroll
      for (int r = 0; r < 4; ++r)
        out[(size_t)(orow0 + fm * 16 + r) * OUT_F + ocol0 + fn * 16] = acc[fm][fn][r];
}

extern "C" void kernel_launch(void* const* d_in, const int* in_sizes, int n_in,
                              void* d_out, int out_size, void* d_ws, size_t ws_size,
                              hipStream_t stream) {
  const float* x      = (const float*)d_in[0];
  const float* gamma  = (const float*)d_in[1];
  const float* beta   = (const float*)d_in[2];
  const float* coeff  = (const float*)d_in[3];
  const float* base_w = (const float*)d_in[4];
  float* out = (float*)d_out;
  _Float16* W2 = (_Float16*)d_ws;   // needs 3072*256*2 = 1.5 MB of workspace

  prep_w<<<dim3(OUT_F), dim3(256), 0, stream>>>(coeff, base_w, W2);
  kan_fused<<<dim3(32768 / BM), dim3(512), 0, stream>>>(x, gamma, beta, W2, out);
}

// Round 4
// 124.334 us; speedup vs baseline: 1.2423x; 1.2423x over previous
//
#include <hip/hip_runtime.h>
#include <hip/hip_bf16.h>

typedef _Float16 f16x8 __attribute__((ext_vector_type(8)));
typedef float f32x4 __attribute__((ext_vector_type(4)));

#define BM 64       // rows per block
#define BKH 96      // K-halves per chunk (8 features x 12 slots)
#define LDA 104     // padded LDS row stride (halves): 208B
#define NCHUNK 32   // 3072 / 96
#define IN_F 256
#define OUT_F 256
#define KDIM 3072   // 256 * 12

// Build W2[o][k] fp16, k = i*12 + m ; m<11 -> coeff[o][i][m], m==11 -> base_w[o][i]
__global__ __launch_bounds__(256) void prep_w(const float* __restrict__ coeff,
                                              const float* __restrict__ base_w,
                                              _Float16* __restrict__ W2) {
  const int o = blockIdx.x;
  for (int k2 = threadIdx.x; k2 < KDIM / 2; k2 += 256) {
    const int k = k2 * 2;
    float v0, v1;
    {
      const int i = k / 12, m = k % 12;
      v0 = (m == 11) ? base_w[o * IN_F + i] : coeff[(o * IN_F + i) * 11 + m];
    }
    {
      const int k1 = k + 1;
      const int i = k1 / 12, m = k1 % 12;
      v1 = (m == 11) ? base_w[o * IN_F + i] : coeff[(o * IN_F + i) * 11 + m];
    }
    union { _Float16 h[2]; unsigned int u; } p;
    p.h[0] = (_Float16)v0;
    p.h[1] = (_Float16)v1;
    *(unsigned int*)&W2[(size_t)o * KDIM + k] = p.u;
  }
}

__global__ __launch_bounds__(256, 2) void kan_fused(const float* __restrict__ x,
                                                    const float* __restrict__ gamma,
                                                    const float* __restrict__ beta,
                                                    const _Float16* __restrict__ W2,
                                                    float* __restrict__ out) {
  __shared__ _Float16 A0[BM * LDA];   // double-buffered A tile (static names ->
  __shared__ _Float16 A1[BM * LDA];   //  compile-time-disjoint LDS regions)
  __shared__ float mu_s[BM], rs_s[BM];
  __shared__ float g_s[IN_F], b_s[IN_F];

  const int tid  = threadIdx.x;
  const int lane = tid & 63;
  const int wid  = tid >> 6;          // 0..3
  const int row0 = blockIdx.x * BM;

  // gamma/beta to LDS (256 threads cover 256 features)
  g_s[tid] = gamma[tid];
  b_s[tid] = beta[tid];

  // ---- LayerNorm stats: one wave per row ----
  for (int rr = wid; rr < BM; rr += 4) {
    const float4 v = *(const float4*)(x + (size_t)(row0 + rr) * IN_F + lane * 4);
    float s  = v.x + v.y + v.z + v.w;
    float sq = v.x * v.x + v.y * v.y + v.z * v.z + v.w * v.w;
    #pragma unroll
    for (int off = 32; off >= 1; off >>= 1) {
      s  += __shfl_xor(s, off);
      sq += __shfl_xor(sq, off);
    }
    if (lane == 0) {
      const float mu  = s * (1.0f / 256.0f);
      const float var = sq * (1.0f / 256.0f) - mu * mu;
      mu_s[rr] = mu;
      rs_s[rr] = 1.0f / sqrtf(var + 1e-5f);
    }
  }

  // wave tile: 4 waves across N, each 64 rows x 64 cols
  const int wc   = wid;               // 0..3
  const int lrow = lane & 15;
  const int lk8  = (lane >> 4) * 8;

  f32x4 acc[4][4] = {};

  // production mapping: 64 rows x 8 features = 512 cells, 2 per thread
  const int prow = tid >> 2;          // 0..63
  const int pfq  = tid & 3;           // feature-pair within chunk

  const _Float16* wbase = W2 + (size_t)(wc * 64 + lrow) * KDIM + lk8;

  auto produce = [&](int c, _Float16* buf) {
    const int i = c * 8 + pfq * 2;
    const float2 xv = *(const float2*)(x + (size_t)(row0 + prow) * IN_F + i);
    const float mu = mu_s[prow], rs = rs_s[prow];
    _Float16 h[24];
    #pragma unroll
    for (int q = 0; q < 2; ++q) {
      const float xr = (q == 0) ? xv.x : xv.y;
      const float n  = (xr - mu) * rs * g_s[i + q] + b_s[i + q];
      const float v  = (n + 1.75f) * 4.0f;      // knots t_j = -1.75 + 0.25*j
      const float fj = floorf(v);
      const int j = (v >= 0.0f && v < 14.0f) ? (int)fj : 999; // out of grid -> zero basis
      const float u  = v - fj;
      const float u2 = u * u, u3 = u2 * u;
      const float w0 = (1.0f / 6.0f) * (1.0f - 3.0f * u + 3.0f * u2 - u3);
      const float w1 = (1.0f / 6.0f) * (3.0f * u3 - 6.0f * u2 + 4.0f);
      const float w2 = (1.0f / 6.0f) * (-3.0f * u3 + 3.0f * u2 + 3.0f * u + 1.0f);
      const float w3 = (1.0f / 6.0f) * u3;
      #pragma unroll
      for (int m = 0; m < 11; ++m) {            // tap index t = m - (j-3)
        const int t = m - j + 3;
        float w = 0.0f;
        w = (t == 0) ? w0 : w;
        w = (t == 1) ? w1 : w;
        w = (t == 2) ? w2 : w;
        w = (t == 3) ? w3 : w;
        h[q * 12 + m] = (_Float16)w;
      }
      h[q * 12 + 11] = (_Float16)(xr / (1.0f + __expf(-xr)));  // silu(raw x)
    }
    char* db = (char*)&buf[prow * LDA] + pfq * 48;
    *(f16x8*)(db)      = *(const f16x8*)&h[0];
    *(f16x8*)(db + 16) = *(const f16x8*)&h[8];
    *(f16x8*)(db + 32) = *(const f16x8*)&h[16];
  };

  auto domfma = [&](int c, const _Float16* buf) {
    const _Float16* wk = wbase + c * BKH;
    #pragma unroll
    for (int fk = 0; fk < 3; ++fk) {
      f16x8 a[4], b[4];
      #pragma unroll
      for (int fm = 0; fm < 4; ++fm)
        a[fm] = *(const f16x8*)&buf[(fm * 16 + lrow) * LDA + fk * 32 + lk8];
      #pragma unroll
      for (int fn = 0; fn < 4; ++fn)
        b[fn] = *(const f16x8*)(wk + (size_t)fn * 16 * KDIM + fk * 32);
      #pragma unroll
      for (int fm = 0; fm < 4; ++fm)
        #pragma unroll
        for (int fn = 0; fn < 4; ++fn)
          acc[fm][fn] = __builtin_amdgcn_mfma_f32_16x16x32_f16(a[fm], b[fn], acc[fm][fn], 0, 0, 0);
    }
  };

  __syncthreads();                    // stats + gamma/beta visible
  produce(0, A0);
  __syncthreads();

  for (int c = 0; c < NCHUNK; c += 2) {
    // interval 1: produce(c+1)->A1 overlaps mfma(c)<-A0
    produce(c + 1, A1);
    domfma(c, A0);
    __syncthreads();
    // interval 2: produce(c+2)->A0 overlaps mfma(c+1)<-A1
    if (c + 2 < NCHUNK) produce(c + 2, A0);
    domfma(c + 1, A1);
    __syncthreads();
  }

  // ---- epilogue: D lane layout col = lane&15, row = (lane>>4)*4 + r ----
  const int orow0 = row0 + (lane >> 4) * 4;
  const int ocol0 = wc * 64 + lrow;
  #pragma unroll
  for (int fm = 0; fm < 4; ++fm)
    #pragma unroll
    for (int fn = 0; fn < 4; ++fn)
      #pragma unroll
      for (int r = 0; r < 4; ++r)
        out[(size_t)(orow0 + fm * 16 + r) * OUT_F + ocol0 + fn * 16] = acc[fm][fn][r];
}

extern "C" void kernel_launch(void* const* d_in, const int* in_sizes, int n_in,
                              void* d_out, int out_size, void* d_ws, size_t ws_size,
                              hipStream_t stream) {
  const float* x      = (const float*)d_in[0];
  const float* gamma  = (const float*)d_in[1];
  const float* beta   = (const float*)d_in[2];
  const float* coeff  = (const float*)d_in[3];
  const float* base_w = (const float*)d_in[4];
  float* out = (float*)d_out;
  _Float16* W2 = (_Float16*)d_ws;   // 3072*256*2 = 1.5 MB of workspace

  prep_w<<<dim3(OUT_F), dim3(256), 0, stream>>>(coeff, base_w, W2);
  kan_fused<<<dim3(32768 / BM), dim3(256), 0, stream>>>(x, gamma, beta, W2, out);
}